// Round 5
// baseline (73.595 us; speedup 1.0000x reference)
//
#include <hip/hip_runtime.h>
#include <hip/hip_fp16.h>

// GeneSymbolCNN: embed(67x32, pad0) -> conv1d k=2/3/4 (32ch) + ReLU + max_t
//                -> concat(96) -> 96x96 linear + ReLU.
// Conv-over-embedding factors into per-token f16 tables:
//   T_{k,h}[v][c] = sum_e embed[v,e] * w_k[c,e,h]  (bias folded into h=0)
// R5 vs R4 (57.5us, VALUBusy 41%, occupancy 19%): the kernel was
// LATENCY-bound at 2 waves/SIMD (grid-capped: 1 thread/row = 512 thr/CU).
// Fix: 2 threads per row (lane pair l, l^1 splits conv positions), grid
// 512x512 -> 2 blocks/CU (2x77184B LDS = 154.4KB <= 160KB) = 16 waves/CU.
// Pair combine via quad_perm DPP (VALU, no LDS) + v_pk_max_f16; projection
// duplicated across the pair (keeps pw wave-uniform -> s_load), stores
// predicated (even lane: outs 0-47, odd: 48-95). Bank-span pattern
// unchanged: rot=(l>>1)&3, par=(l>>3)&1 -> 8 lanes/span, data-independent.

#define VOCABSZ 67
#define EMBSZ   32
#define NCH     32
#define NFEAT   96
#define SEQL    16
#define BATCH   131072
#define NTAB    9
#define NENT    (NTAB * VOCABSZ)           // 603 table entries
#define TABU    (NENT * NCH / 2)           // 9648 u32 words of f16 tables
#define PWOFF   TABU                       // packed pw follows tables in ws
#define NFP     (NFEAT / 2)                // 48 feature pairs
#define NPW     (NFEAT * NFP)              // 4608 packed pw words
#define LDSB    (NENT * 128)               // 77184 B replicated tables
#define TSTRB   8576                       // 67*128 B per table

typedef _Float16 v2h __attribute__((ext_vector_type(2)));
typedef _Float16 v8h __attribute__((ext_vector_type(8)));

__device__ __forceinline__ unsigned packh2(float a, float b) {
    v2h p; p[0] = (_Float16)a; p[1] = (_Float16)b;
    return __builtin_bit_cast(unsigned, p);
}

__device__ __forceinline__ float dot2acc(v2h a, v2h b, float c) {
#if __has_builtin(__builtin_amdgcn_fdot2)
    return __builtin_amdgcn_fdot2(a, b, c, false);   // v_dot2_f32_f16
#else
    return c + (float)a[0] * (float)b[0] + (float)a[1] * (float)b[1];
#endif
}

// ------------- kernel 1: f16 tables + packed pw into d_ws ------------------
__global__ __launch_bounds__(256) void build_tables(
    const float* __restrict__ embed,
    const float* __restrict__ w2, const float* __restrict__ b2,
    const float* __restrict__ w3, const float* __restrict__ b3,
    const float* __restrict__ w4, const float* __restrict__ b4,
    const float* __restrict__ pw,
    unsigned* __restrict__ ws)
{
    int idx = blockIdx.x * 256 + threadIdx.x;
    if (idx < TABU) {                      // one half2 (2 channels) per thread
        int cp = idx & 15;                 // channel pair 0..15
        int t  = idx >> 4;                 // j*67 + v
        int j  = t / VOCABSZ;
        int v  = t - j * VOCABSZ;
        const float* w; const float* bias; int k, h;
        if (j < 2)      { w = w2; k = 2; h = j;     bias = (h == 0) ? b2 : nullptr; }
        else if (j < 5) { w = w3; k = 3; h = j - 2; bias = (h == 0) ? b3 : nullptr; }
        else            { w = w4; k = 4; h = j - 5; bias = (h == 0) ? b4 : nullptr; }
        int c0 = 2 * cp;
        float a0 = bias ? bias[c0]     : 0.0f;
        float a1 = bias ? bias[c0 + 1] : 0.0f;
        if (v != 0) {                      // padding_idx=0: row 0 is zeros
            #pragma unroll
            for (int e = 0; e < EMBSZ; ++e) {
                float ev = embed[v * EMBSZ + e];
                a0 += ev * w[((c0    ) * EMBSZ + e) * k + h];
                a1 += ev * w[((c0 + 1) * EMBSZ + e) * k + h];
            }
        }
        ws[t * 16 + cp] = packh2(a0, a1);
    } else if (idx < TABU + NPW) {         // packed pw: pwh[o][fp]
        int i  = idx - TABU;
        int o  = i / NFP;
        int fp = i - o * NFP;
        ws[PWOFF + i] = packh2(pw[o * NFEAT + 2 * fp], pw[o * NFEAT + 2 * fp + 1]);
    }
}

// ------------- kernel 2: fused conv-as-lookup + max + projection -----------
__device__ __forceinline__ void unrot(v2h (&m)[16], bool r1, bool r2) {
    // canon group g = slot (g - rot) & 3 (groups of 4 half2 = one 16B chunk)
    v2h t[16];
    #pragma unroll
    for (int j = 0; j < 4; ++j) {
        t[0 + j]  = r1 ? m[12 + j] : m[0 + j];
        t[4 + j]  = r1 ? m[0 + j]  : m[4 + j];
        t[8 + j]  = r1 ? m[4 + j]  : m[8 + j];
        t[12 + j] = r1 ? m[8 + j]  : m[12 + j];
    }
    #pragma unroll
    for (int j = 0; j < 4; ++j) {
        m[0 + j]  = r2 ? t[8 + j]  : t[0 + j];
        m[4 + j]  = r2 ? t[12 + j] : t[4 + j];
        m[8 + j]  = r2 ? t[0 + j]  : t[8 + j];
        m[12 + j] = r2 ? t[4 + j]  : t[12 + j];
    }
}

#define MAXACC(M, Q, S) \
    M[4*(Q)+0] = __builtin_elementwise_max(M[4*(Q)+0], __builtin_shufflevector(S, S, 0, 1)); \
    M[4*(Q)+1] = __builtin_elementwise_max(M[4*(Q)+1], __builtin_shufflevector(S, S, 2, 3)); \
    M[4*(Q)+2] = __builtin_elementwise_max(M[4*(Q)+2], __builtin_shufflevector(S, S, 4, 5)); \
    M[4*(Q)+3] = __builtin_elementwise_max(M[4*(Q)+3], __builtin_shufflevector(S, S, 6, 7));

// N conv positions (P0..P0+N-1) of a K-tap conv, first table at byte TB.
// All indices compile-time after unroll (rule #20). Loads grouped per tap.
template<int K, int N, int P0, int TB, int SZ>
__device__ __forceinline__ void convbatch(const char* __restrict__ base,
                                          const int (&a)[SZ], int co,
                                          v2h (&m)[16], int q)
{
    v8h s[N];
    #pragma unroll
    for (int u = 0; u < N; ++u)
        s[u] = *reinterpret_cast<const v8h*>(base + TB + a[P0 + u] + co);
    #pragma unroll
    for (int h = 1; h < K; ++h) {
        v8h t[N];
        #pragma unroll
        for (int u = 0; u < N; ++u)
            t[u] = *reinterpret_cast<const v8h*>(base + TB + h * TSTRB + a[P0 + u + h] + co);
        #pragma unroll
        for (int u = 0; u < N; ++u) s[u] = s[u] + t[u];
    }
    #pragma unroll
    for (int u = 0; u < N; ++u) { MAXACC(m, q, s[u]) }
}

__device__ __forceinline__ v2h dppmax(v2h v) {
    // partner = lane^1 via quad_perm [1,0,3,2]; VALU-only, no LDS traffic.
    int p = __builtin_amdgcn_mov_dpp(__builtin_bit_cast(int, v),
                                     0xB1, 0xF, 0xF, true);
    return __builtin_elementwise_max(v, __builtin_bit_cast(v2h, p));
}

__global__ __launch_bounds__(512, 4) void fused_cnn(
    const int*      __restrict__ x,
    const unsigned* __restrict__ ws,
    const float*    __restrict__ pb,
    float*          __restrict__ out)
{
    extern __shared__ __align__(16) char ldsraw[];
    const int tid = threadIdx.x;
    {   // stage + replicate: 2412 source float4 -> 2 LDS copies each.
        const float4* s4 = reinterpret_cast<const float4*>(ws);
        float4* d4 = reinterpret_cast<float4*>(ldsraw);
        #pragma unroll
        for (int i0 = 0; i0 < 2560; i0 += 512) {
            int i = i0 + tid;
            if (i < 2412) {
                int t = i >> 2;
                int c = (i + t) & 3;
                float4 v = s4[t * 4 + c];
                d4[t * 8 + c]     = v;   // parity 0
                d4[t * 8 + 4 + c] = v;   // parity 1 (+64 B)
            }
        }
    }
    __syncthreads();

    const int lane = tid & 63;
    const int sel  = lane & 1;                   // position-half of the pair
    const int rot  = (lane >> 1) & 3;            // chunk rotation
    const int par  = ((lane >> 3) & 1) << 6;     // 64B parity replica
    const int row  = (blockIdx.x * 512 + tid) >> 1;  // pair shares a row
    const char* base = ldsraw;

    const int4* xp = reinterpret_cast<const int4*>(x + row * SEQL);
    int4 q0 = xp[0], q1 = xp[1], q2 = xp[2], q3 = xp[3];
    int vb[16];                                   // byte offset of entry line
    vb[ 0] = q0.x << 7; vb[ 1] = q0.y << 7; vb[ 2] = q0.z << 7; vb[ 3] = q0.w << 7;
    vb[ 4] = q1.x << 7; vb[ 5] = q1.y << 7; vb[ 6] = q1.z << 7; vb[ 7] = q1.w << 7;
    vb[ 8] = q2.x << 7; vb[ 9] = q2.y << 7; vb[10] = q2.z << 7; vb[11] = q2.w << 7;
    vb[12] = q3.x << 7; vb[13] = q3.y << 7; vb[14] = q3.z << 7; vb[15] = q3.w << 7;

    // Per-pair shifted token arrays (compile-time indices, runtime select):
    // conv2: even p=0..7, odd p=7..14 (p=7 dup); conv3: even 0..6, odd 7..13;
    // conv4: even 0..6, odd 6..12 (p=6 dup). Max is idempotent -> dups ok.
    int a2[9], a3[9], a4[10];
    #pragma unroll
    for (int u = 0; u < 9; ++u)  a2[u] = sel ? vb[u + 7] : vb[u];
    #pragma unroll
    for (int u = 0; u < 9; ++u)  a3[u] = sel ? vb[u + 7] : vb[u];
    #pragma unroll
    for (int u = 0; u < 10; ++u) a4[u] = sel ? vb[u + 6] : vb[u];

    v2h m2[16], m3[16], m4[16];
    #pragma unroll
    for (int i = 0; i < 16; ++i) { m2[i] = 0; m3[i] = 0; m4[i] = 0; }

    #pragma unroll
    for (int q = 0; q < 4; ++q) {                 // 16B chunk step, lane-rotated
        const int co = (((q + rot) & 3) << 4) + par;
        // conv2: tables 0,1 ; 8 positions
        convbatch<2, 4, 0, 0 * TSTRB>(base, a2, co, m2, q);
        convbatch<2, 4, 4, 0 * TSTRB>(base, a2, co, m2, q);
        // conv3: tables 2,3,4 ; 7 positions
        convbatch<3, 4, 0, 2 * TSTRB>(base, a3, co, m3, q);
        convbatch<3, 3, 4, 2 * TSTRB>(base, a3, co, m3, q);
        // conv4: tables 5,6,7,8 ; 7 positions
        convbatch<4, 3, 0, 5 * TSTRB>(base, a4, co, m4, q);
        convbatch<4, 2, 3, 5 * TSTRB>(base, a4, co, m4, q);
        convbatch<4, 2, 5, 5 * TSTRB>(base, a4, co, m4, q);
    }

    const bool r1 = (rot & 1) != 0, r2b = (rot & 2) != 0;
    unrot(m2, r1, r2b);
    unrot(m3, r1, r2b);
    unrot(m4, r1, r2b);

    // combine the pair's position-halves: lane <-> lane^1, elementwise max.
    #pragma unroll
    for (int i = 0; i < 16; ++i) {
        m2[i] = dppmax(m2[i]); m3[i] = dppmax(m3[i]); m4[i] = dppmax(m4[i]);
    }

    // projection (duplicated across the pair; pw/pb stay wave-uniform).
    const unsigned* __restrict__ pwh = ws + PWOFF;
    float* orow = out + (size_t)row * NFEAT;
    #pragma unroll 1
    for (int ob = 0; ob < NFEAT; ob += 8) {
        float acc[8];
        #pragma unroll
        for (int k = 0; k < 8; ++k) acc[k] = pb[ob + k];
        #pragma unroll
        for (int fp = 0; fp < NFP; ++fp) {
            v2h fv = (fp < 16) ? m2[fp] : ((fp < 32) ? m3[fp - 16] : m4[fp - 32]);
            #pragma unroll
            for (int k = 0; k < 8; ++k) {
                v2h wv = __builtin_bit_cast(v2h, pwh[(ob + k) * NFP + fp]);
                acc[k] = dot2acc(fv, wv, acc[k]);
            }
        }
        if ((ob >= 48) == (sel != 0)) {          // even lane: 0-47, odd: 48-95
            float4 o0 = make_float4(fmaxf(acc[0], 0.f), fmaxf(acc[1], 0.f),
                                    fmaxf(acc[2], 0.f), fmaxf(acc[3], 0.f));
            float4 o1 = make_float4(fmaxf(acc[4], 0.f), fmaxf(acc[5], 0.f),
                                    fmaxf(acc[6], 0.f), fmaxf(acc[7], 0.f));
            *reinterpret_cast<float4*>(orow + ob)     = o0;
            *reinterpret_cast<float4*>(orow + ob + 4) = o1;
        }
    }
}

extern "C" void kernel_launch(void* const* d_in, const int* in_sizes, int n_in,
                              void* d_out, int out_size, void* d_ws, size_t ws_size,
                              hipStream_t stream)
{
    const int*   x     = (const int*)  d_in[0];
    const float* embed = (const float*)d_in[1];
    const float* w2    = (const float*)d_in[2];
    const float* b2    = (const float*)d_in[3];
    const float* w3    = (const float*)d_in[4];
    const float* b3    = (const float*)d_in[5];
    const float* w4    = (const float*)d_in[6];
    const float* b4    = (const float*)d_in[7];
    const float* pw    = (const float*)d_in[8];
    const float* pb    = (const float*)d_in[9];
    float* out = (float*)d_out;
    unsigned* ws = (unsigned*)d_ws;      // 9648 + 4608 u32 = 57 KB used

    build_tables<<<(TABU + NPW + 255) / 256, 256, 0, stream>>>(
        embed, w2, b2, w3, b3, w4, b4, pw, ws);

    (void)hipFuncSetAttribute((const void*)fused_cnn,
                              hipFuncAttributeMaxDynamicSharedMemorySize,
                              LDSB);
    // 512 blocks x 512 threads: 2 threads/row, 2 blocks/CU -> 16 waves/CU.
    fused_cnn<<<BATCH / 256, 512, LDSB, stream>>>(x, ws, pb, out);
}

// Round 6
// 45.553 us; speedup vs baseline: 1.6156x; 1.6156x over previous
//
#include <hip/hip_runtime.h>
#include <hip/hip_fp16.h>

// GeneSymbolCNN: embed(67x32, pad0) -> conv1d k=2/3/4 (32ch) + ReLU + max_t
//                -> concat(96) -> 96x96 linear + ReLU.
// Conv-over-embedding factors into per-token f16 tables:
//   T_{k,h}[v][c] = sum_e embed[v,e] * w_k[c,e,h]  (bias folded into h=0)
// R6 vs R5 (67us, VALU-bound from duplicated dot2 projection):
//  * 4 threads/row split by CHANNEL-CHUNK c = lane>>4 (8 channels each).
//    Thread's conv output (v8h m2,m3,m4) IS the mfma_f32_16x16x32_f16
//    A-fragment for its (row = lane&15, k-group = c): feats 8c..8c+7 of
//    each 32-feat k-tile. Projection = 18 MFMAs/wave (16 rows x 96 outs),
//    replacing 4608 dot2/thread. C layout (m89-verified): col=lane&15,
//    row=(lane>>4)*4+reg -> coalesced 64B store runs.
//  * LDS: parity-replicated 128B lines (as R4); span = c + 4*par is FIXED
//    per lane -> exactly 8 lanes/span every instruction, data-independent.
//  * No rotation/unrot/DPP needed; VGPR ~110 -> 16 waves/CU at
//    __launch_bounds__(512,4). LDS pipe (~1e6 b128 wave-instrs) is the
//    predicted floor (~25us).

#define VOCABSZ 67
#define EMBSZ   32
#define NCH     32
#define NFEAT   96
#define SEQL    16
#define BATCH   131072
#define NTAB    9
#define NENT    (NTAB * VOCABSZ)           // 603 table entries
#define TABU    (NENT * NCH / 2)           // 9648 u32 words of f16 tables
#define PWOFF   TABU                       // packed pw follows tables in ws
#define NFP     (NFEAT / 2)                // 48 feature pairs
#define NPW     (NFEAT * NFP)              // 4608 packed pw words
#define LDSB    (NENT * 128)               // 77184 B replicated tables
#define TSTRB   (VOCABSZ * 128)            // 8576 B per table

typedef _Float16 v2h __attribute__((ext_vector_type(2)));
typedef _Float16 v8h __attribute__((ext_vector_type(8)));
typedef float    v4f __attribute__((ext_vector_type(4)));

__device__ __forceinline__ unsigned packh2(float a, float b) {
    v2h p; p[0] = (_Float16)a; p[1] = (_Float16)b;
    return __builtin_bit_cast(unsigned, p);
}

// ------------- kernel 1: f16 tables + packed pw into d_ws ------------------
__global__ __launch_bounds__(256) void build_tables(
    const float* __restrict__ embed,
    const float* __restrict__ w2, const float* __restrict__ b2,
    const float* __restrict__ w3, const float* __restrict__ b3,
    const float* __restrict__ w4, const float* __restrict__ b4,
    const float* __restrict__ pw,
    unsigned* __restrict__ ws)
{
    int idx = blockIdx.x * 256 + threadIdx.x;
    if (idx < TABU) {                      // one half2 (2 channels) per thread
        int cp = idx & 15;                 // channel pair 0..15
        int t  = idx >> 4;                 // j*67 + v
        int j  = t / VOCABSZ;
        int v  = t - j * VOCABSZ;
        const float* w; const float* bias; int k, h;
        if (j < 2)      { w = w2; k = 2; h = j;     bias = (h == 0) ? b2 : nullptr; }
        else if (j < 5) { w = w3; k = 3; h = j - 2; bias = (h == 0) ? b3 : nullptr; }
        else            { w = w4; k = 4; h = j - 5; bias = (h == 0) ? b4 : nullptr; }
        int c0 = 2 * cp;
        float a0 = bias ? bias[c0]     : 0.0f;
        float a1 = bias ? bias[c0 + 1] : 0.0f;
        if (v != 0) {                      // padding_idx=0: row 0 is zeros
            #pragma unroll
            for (int e = 0; e < EMBSZ; ++e) {
                float ev = embed[v * EMBSZ + e];
                a0 += ev * w[((c0    ) * EMBSZ + e) * k + h];
                a1 += ev * w[((c0 + 1) * EMBSZ + e) * k + h];
            }
        }
        ws[t * 16 + cp] = packh2(a0, a1);
    } else if (idx < TABU + NPW) {         // packed pw: pwh[o][fp]
        int i  = idx - TABU;
        int o  = i / NFP;
        int fp = i - o * NFP;
        ws[PWOFF + i] = packh2(pw[o * NFEAT + 2 * fp], pw[o * NFEAT + 2 * fp + 1]);
    }
}

// ------------- kernel 2: fused conv-as-lookup + max + MFMA projection ------
// N conv positions (P0..P0+N-1) of a K-tap conv, first table at byte TB.
// All indices compile-time after unroll (rule #20). N loads in flight/tap.
template<int K, int N, int P0, int TB>
__device__ __forceinline__ void convbatch(const char* __restrict__ base,
                                          const int (&ap)[16], v8h& m)
{
    v8h s[N];
    #pragma unroll
    for (int u = 0; u < N; ++u)
        s[u] = *reinterpret_cast<const v8h*>(base + TB + ap[P0 + u]);
    #pragma unroll
    for (int h = 1; h < K; ++h) {
        v8h t[N];
        #pragma unroll
        for (int u = 0; u < N; ++u)
            t[u] = *reinterpret_cast<const v8h*>(base + TB + h * TSTRB + ap[P0 + u + h]);
        #pragma unroll
        for (int u = 0; u < N; ++u) s[u] = s[u] + t[u];
    }
    #pragma unroll
    for (int u = 0; u < N; ++u) m = __builtin_elementwise_max(m, s[u]);
}

__global__ __launch_bounds__(512, 4) void fused_cnn(
    const int*      __restrict__ x,
    const unsigned* __restrict__ ws,
    const float*    __restrict__ pb,
    float*          __restrict__ out)
{
    extern __shared__ __align__(16) char ldsraw[];
    const int tid = threadIdx.x;
    {   // stage + parity-replicate: 2412 source float4 -> 2 LDS copies each
        const float4* s4 = reinterpret_cast<const float4*>(ws);
        float4* d4 = reinterpret_cast<float4*>(ldsraw);
        #pragma unroll
        for (int i0 = 0; i0 < 2560; i0 += 512) {
            int i = i0 + tid;
            if (i < 2412) {
                int t = i >> 2;
                int c = (i + t) & 3;
                float4 v = s4[t * 4 + c];
                d4[t * 8 + c]     = v;   // parity 0
                d4[t * 8 + 4 + c] = v;   // parity 1 (+64 B)
            }
        }
    }
    __syncthreads();

    const int lane = tid & 63;
    const int wv   = tid >> 6;               // wave 0..7
    const int ml   = lane & 15;              // row within wave's 16-row tile
    const int c    = lane >> 4;              // fixed chunk = MFMA k-group
    const int par  = (lane >> 3) & 1;        // parity replica choice
    const int co   = (c << 4) + (par << 6);  // byte offset within 128B line
    const int rowb = blockIdx.x * 128 + wv * 16;
    const int row  = rowb + ml;
    const char* base = ldsraw;

    const int4* xp = reinterpret_cast<const int4*>(x + row * SEQL);
    int4 q0 = xp[0], q1 = xp[1], q2 = xp[2], q3 = xp[3];
    int ap[16];                               // line offset + lane chunk/parity
    ap[ 0] = (q0.x << 7) + co; ap[ 1] = (q0.y << 7) + co;
    ap[ 2] = (q0.z << 7) + co; ap[ 3] = (q0.w << 7) + co;
    ap[ 4] = (q1.x << 7) + co; ap[ 5] = (q1.y << 7) + co;
    ap[ 6] = (q1.z << 7) + co; ap[ 7] = (q1.w << 7) + co;
    ap[ 8] = (q2.x << 7) + co; ap[ 9] = (q2.y << 7) + co;
    ap[10] = (q2.z << 7) + co; ap[11] = (q2.w << 7) + co;
    ap[12] = (q3.x << 7) + co; ap[13] = (q3.y << 7) + co;
    ap[14] = (q3.z << 7) + co; ap[15] = (q3.w << 7) + co;

    v8h m2 = {}, m3 = {}, m4 = {};            // feat >= 0, so 0-init is max-safe

    // conv2: tables 0,1 ; positions 0..14
    convbatch<2, 5,  0, 0 * TSTRB>(base, ap, m2);
    convbatch<2, 5,  5, 0 * TSTRB>(base, ap, m2);
    convbatch<2, 5, 10, 0 * TSTRB>(base, ap, m2);
    // conv3: tables 2,3,4 ; positions 0..13
    convbatch<3, 5,  0, 2 * TSTRB>(base, ap, m3);
    convbatch<3, 5,  5, 2 * TSTRB>(base, ap, m3);
    convbatch<3, 4, 10, 2 * TSTRB>(base, ap, m3);
    // conv4: tables 5,6,7,8 ; positions 0..12
    convbatch<4, 5,  0, 5 * TSTRB>(base, ap, m4);
    convbatch<4, 4,  5, 5 * TSTRB>(base, ap, m4);
    convbatch<4, 4,  9, 5 * TSTRB>(base, ap, m4);

    // ---- projection: O[16 rows][96] = feat x pw^T via 18 mfma 16x16x32 ----
    // A-fragment: lane holds A[ml][8c..8c+7] per k-tile = m2/m3/m4 directly.
    // B-fragment: lane needs pw[n = ml + 16u][k = 32t + 8c .. +7] ->
    //   pwh u32 index (16u+ml)*48 + 16t + 4c; 16B vector load, L1-resident.
    const unsigned* __restrict__ pwp = ws + PWOFF + ml * NFP + c * 4;
    #pragma unroll
    for (int u = 0; u < 6; ++u) {
        v4f acc = {0.f, 0.f, 0.f, 0.f};
        v8h b0 = *reinterpret_cast<const v8h*>(pwp + 768 * u);
        v8h b1 = *reinterpret_cast<const v8h*>(pwp + 768 * u + 16);
        v8h b2 = *reinterpret_cast<const v8h*>(pwp + 768 * u + 32);
        acc = __builtin_amdgcn_mfma_f32_16x16x32_f16(m2, b0, acc, 0, 0, 0);
        acc = __builtin_amdgcn_mfma_f32_16x16x32_f16(m3, b1, acc, 0, 0, 0);
        acc = __builtin_amdgcn_mfma_f32_16x16x32_f16(m4, b2, acc, 0, 0, 0);
        // D: row m = c*4 + r (local), col n = 16u + ml. Bias + ReLU at store.
        float pbl = pb[16 * u + ml];
        #pragma unroll
        for (int r = 0; r < 4; ++r)
            out[(size_t)(rowb + c * 4 + r) * NFEAT + 16 * u + ml] =
                fmaxf(acc[r] + pbl, 0.f);
    }
}

extern "C" void kernel_launch(void* const* d_in, const int* in_sizes, int n_in,
                              void* d_out, int out_size, void* d_ws, size_t ws_size,
                              hipStream_t stream)
{
    const int*   x     = (const int*)  d_in[0];
    const float* embed = (const float*)d_in[1];
    const float* w2    = (const float*)d_in[2];
    const float* b2    = (const float*)d_in[3];
    const float* w3    = (const float*)d_in[4];
    const float* b3    = (const float*)d_in[5];
    const float* w4    = (const float*)d_in[6];
    const float* b4    = (const float*)d_in[7];
    const float* pw    = (const float*)d_in[8];
    const float* pb    = (const float*)d_in[9];
    float* out = (float*)d_out;
    unsigned* ws = (unsigned*)d_ws;      // 9648 + 4608 u32 = 57 KB used

    build_tables<<<(TABU + NPW + 255) / 256, 256, 0, stream>>>(
        embed, w2, b2, w3, b3, w4, b4, pw, ws);

    (void)hipFuncSetAttribute((const void*)fused_cnn,
                              hipFuncAttributeMaxDynamicSharedMemorySize,
                              LDSB);
    // 4 threads/row, 128 rows/block -> grid 1024; 2 blocks/CU (154.4KB LDS),
    // 16 waves/CU at VGPR<=128.
    fused_cnn<<<BATCH / 128, 512, LDSB, stream>>>(x, ws, pb, out);
}